// Round 11
// baseline (103.524 us; speedup 1.0000x reference)
//
#include <hip/hip_runtime.h>
#include <hip/hip_bf16.h>

#define IDIM 64
#define RDIM 36
#define DDIM 1024
#define CDIM 64
#define WDIM 32
#define SMOOTH 9.0f
#define EPSF 1e-8f

typedef __bf16 bf16_t;
typedef __bf16 bf16x8 __attribute__((ext_vector_type(8)));
typedef __bf16 bf16x4 __attribute__((ext_vector_type(4)));
typedef float f32x4 __attribute__((ext_vector_type(4)));

#define MFMA16(a, b, c) __builtin_amdgcn_mfma_f32_16x16x32_bf16((a), (b), (c), 0, 0, 0)

// async global->LDS DMA, 16B/lane; LDS dest is wave-uniform base + lane*16
typedef __attribute__((address_space(1))) const void glb_as;
typedef __attribute__((address_space(3))) void lds_as;
#define GLDS16(g, l) __builtin_amdgcn_global_load_lds((glb_as*)(g), (lds_as*)(l), 16, 0, 0)

// ---------- workspace layout (bytes) ----------
// imgsB: frag-permuted imgs, rows padded to 48 with zeros.
//   elem off = ((((i*4+wvk)*8+kk)*3+nt)*64 + lane)*8 ; lane=(qd*16+l15)
// capsA: ((((c*4+wvk)*8+kk)*2+mt)*64 + lane)*8
// Gfrag: bf16 B-layout frags of Gram, per i: [(kk*3+nt)*64+lane]*8, kk in {0,1}
#define IMGSB_OFF 0
#define IMGSB_BYTES (IDIM * 4 * 8 * 3 * 512 * 2)            // 6 MB
#define CAPSA_OFF (IMGSB_OFF + IMGSB_BYTES)
#define CAPSA_BYTES (CDIM * 4 * 8 * 2 * 512 * 2)            // 4 MB
#define GF_OFF    (CAPSA_OFF + CAPSA_BYTES)
#define GF_BYTES  (IDIM * 384 * 8 * 2)                      // 384 KB
#define CAPN_OFF  (GF_OFF + GF_BYTES)

// =====================================================================
// Kernel 1 (R10 verbatim): FUSED prep + gram, 128 blocks.
// Blocks 0..63 (one image i): fp32->bf16 transpose/convert, frags to
// global AND LDS fragL; Gram via MFMA from fragL; Gfrag written.
// Blocks 64..127 (one caption c): caps convert + fp32 norms.
// =====================================================================
__global__ __launch_bounds__(256) void prep_fused(
    const float* __restrict__ imgs, const float* __restrict__ caps,
    bf16_t* __restrict__ imgsB, bf16_t* __restrict__ capsA,
    bf16_t* __restrict__ Gfrag, float* __restrict__ capnorm) {
  __shared__ __align__(16) char smem0[4 * 48 * 49 * 4];   // ldsb | part overlay
  __shared__ __align__(16) bf16_t fragL[4][12288];        // 96 KB frag copy
  bf16_t* ldsb = (bf16_t*)smem0;                          // [36*264]
  float (*part)[48][49] = (float(*)[48][49])smem0;        // [4][48][49]

  int b = blockIdx.x, tid = threadIdx.x;
  int wv = tid >> 6, ln = tid & 63;
  int l15 = ln & 15, qd = ln >> 4;

  if (b < 64) {
    int i = b;
    // ---- phase 1: convert/transpose 4 K-slices ----
    for (int wvk = 0; wvk < 4; ++wvk) {
      const float* src = imgs + (size_t)i * RDIM * DDIM + wvk * 256;
#pragma unroll
      for (int rep = 0; rep < 9; ++rep) {          // 36 rows x 64 float4
        int idx = rep * 256 + tid;
        int row = idx >> 6, q = idx & 63;
        float4 v = *(const float4*)(src + (size_t)row * DDIM + q * 4);
        bf16x4 p;
        p[0] = (bf16_t)v.x; p[1] = (bf16_t)v.y; p[2] = (bf16_t)v.z; p[3] = (bf16_t)v.w;
        *(bf16x4*)&ldsb[row * 264 + q * 4] = p;
      }
      __syncthreads();
      bf16_t* dst = imgsB + (size_t)(i * 4 + wvk) * 12288;
#pragma unroll
      for (int rep = 0; rep < 6; ++rep) {          // 1536 frag units of 8
        int u = rep * 256 + tid;
        int kk = u / 192, rem = u - kk * 192;
        int nt = rem >> 6, lane = rem & 63, qd2 = lane >> 4, l152 = lane & 15;
        int row = nt * 16 + l152;
        bf16x8 p;
        if (row < 36) {
          p = *(const bf16x8*)&ldsb[row * 264 + kk * 32 + qd2 * 8];
        } else {
#pragma unroll
          for (int j = 0; j < 8; ++j) p[j] = (bf16_t)0.0f;
        }
        *(bf16x8*)(dst + (size_t)u * 8) = p;       // global, coalesced
        *(bf16x8*)&fragL[wvk][u * 8] = p;          // LDS copy for gram
      }
      __syncthreads();
    }
    // ---- phase 2: Gram via MFMA from fragL ----
    f32x4 acc[3][3];
#pragma unroll
    for (int mt = 0; mt < 3; ++mt)
#pragma unroll
      for (int nt = 0; nt < 3; ++nt) {
        f32x4 zf = {0.f, 0.f, 0.f, 0.f};
        acc[mt][nt] = zf;
      }
#pragma unroll
    for (int kk = 0; kk < 8; ++kk) {
      bf16x8 a[3];
#pragma unroll
      for (int nt = 0; nt < 3; ++nt)
        a[nt] = *(const bf16x8*)&fragL[wv][((kk * 3 + nt) * 64 + ln) * 8];
#pragma unroll
      for (int mt = 0; mt < 3; ++mt)
#pragma unroll
        for (int nt = 0; nt < 3; ++nt)
          acc[mt][nt] = MFMA16(a[mt], a[nt], acc[mt][nt]);
    }
#pragma unroll
    for (int mt = 0; mt < 3; ++mt)
#pragma unroll
      for (int nt = 0; nt < 3; ++nt)
#pragma unroll
        for (int rg = 0; rg < 4; ++rg)
          part[wv][mt * 16 + qd * 4 + rg][nt * 16 + l15] = acc[mt][nt][rg];
    __syncthreads();
    for (int idx = tid; idx < 384; idx += 256) {
      int kk = idx / 192;
      int rem = idx - kk * 192;
      int nt = rem >> 6, lnn = rem & 63;
      int qd2 = lnn >> 4, l152 = lnn & 15;
      int n = nt * 16 + l152;
      bf16x8 pk;
#pragma unroll
      for (int j = 0; j < 8; ++j) {
        int k = kk * 32 + qd2 * 8 + j;
        float v = (k < 48) ? (part[0][k][n] + part[1][k][n] + part[2][k][n] + part[3][k][n]) : 0.f;
        pk[j] = (bf16_t)v;
      }
      *(bf16x8*)(Gfrag + ((size_t)i * 384 + idx) * 8) = pk;
    }
  } else {
    // ---- caps branch: convert + fp32 norms ----
    int c = b - 64;
    const float* src = caps + (size_t)c * WDIM * DDIM;
    float ss[8];
#pragma unroll
    for (int rep = 0; rep < 8; ++rep) ss[rep] = 0.f;
    for (int wvk = 0; wvk < 4; ++wvk) {
#pragma unroll
      for (int rep = 0; rep < 8; ++rep) {          // 32 rows x 64 float4
        int idx = rep * 256 + tid;
        int row = idx >> 6, q = idx & 63;
        float4 v = *(const float4*)(src + (size_t)row * DDIM + wvk * 256 + q * 4);
        ss[rep] += v.x * v.x + v.y * v.y + v.z * v.z + v.w * v.w;
        bf16x4 p;
        p[0] = (bf16_t)v.x; p[1] = (bf16_t)v.y; p[2] = (bf16_t)v.z; p[3] = (bf16_t)v.w;
        *(bf16x4*)&ldsb[row * 264 + q * 4] = p;
      }
      __syncthreads();
      bf16_t* dst = capsA + (size_t)(c * 4 + wvk) * 8192;
#pragma unroll
      for (int rep = 0; rep < 4; ++rep) {          // 1024 frag units
        int u = rep * 256 + tid;
        int kk = u >> 7, rem = u & 127;
        int mt = rem >> 6, lane = rem & 63, qd2 = lane >> 4, l152 = lane & 15;
        int row = mt * 16 + l152;
        bf16x8 p = *(const bf16x8*)&ldsb[row * 264 + kk * 32 + qd2 * 8];
        *(bf16x8*)(dst + (size_t)u * 8) = p;
      }
      __syncthreads();
    }
#pragma unroll
    for (int rep = 0; rep < 8; ++rep) {
      float s = ss[rep];
#pragma unroll
      for (int off = 32; off >= 1; off >>= 1) s += __shfl_xor(s, off, 64);
      if (ln == rep) capnorm[c * 32 + rep * 4 + wv] = sqrtf(s);
    }
  }
}

// =====================================================================
// Kernel 2: main — R10 structure; B staged via ASYNC global_load_lds
// (16B/lane DMA, no VGPR round-trip); launch_bounds(256,5) caps VGPR
// at 102 -> 5 blocks/CU (LDS 5 x 24.6KB = 123KB fits).
// =====================================================================
__global__ __launch_bounds__(256, 5) void main_kernel(
    const bf16_t* __restrict__ capsA, const bf16_t* __restrict__ imgsB,
    const bf16_t* __restrict__ Gfrag, const float* __restrict__ capnorm,
    const int* __restrict__ cap_lens, float* __restrict__ out) {
  __shared__ __align__(16) bf16_t ldsB[2][6144];   // 24.6 KB B chunks / attn scratch

  int bx = blockIdx.x;
  int wv = threadIdx.x >> 6, ln = threadIdx.x & 63;
  int l15 = ln & 15, qd = ln >> 4;
  int xcd = bx & 7, rest = bx >> 3;
  int ih = rest & 7, cq = rest >> 3;
  int i = xcd * 8 + ih;                 // XCD keeps an 8-image octet L2-resident
  int c = cq * 4 + wv;
  int clen = cap_lens[c];

  const bf16_t* Ab = capsA + (size_t)c * 32768;
  const bf16_t* Bb = imgsB + (size_t)i * 49152;

  // async stage chunk 0: wave's quarter = 3 x 1KB DMA (lane*16B pattern)
  {
    const bf16_t* gp = Bb + wv * 1536 + ln * 8;
    bf16_t* lp = &ldsB[0][wv * 1536];           // wave-uniform base
    GLDS16(gp, lp);
    GLDS16(gp + 512, lp + 512);
    GLDS16(gp + 1024, lp + 1024);
  }
  __syncthreads();   // drains DMA (vmcnt) + publishes chunk 0

  f32x4 acc[2][3];
#pragma unroll
  for (int mt = 0; mt < 2; ++mt)
#pragma unroll
    for (int nt = 0; nt < 3; ++nt) {
      f32x4 zf = {0.f, 0.f, 0.f, 0.f};
      acc[mt][nt] = zf;
    }

  for (int ch = 0; ch < 8; ++ch) {
    int p = ch & 1;
    if (ch < 7) {  // async-issue next chunk into the other buffer
      const bf16_t* gp = Bb + (ch + 1) * 6144 + wv * 1536 + ln * 8;
      bf16_t* lp = &ldsB[1 - p][wv * 1536];
      GLDS16(gp, lp);
      GLDS16(gp + 512, lp + 512);
      GLDS16(gp + 1024, lp + 1024);
    }
#pragma unroll
    for (int j = 0; j < 4; ++j) {
      int s = ch * 4 + j;
      const bf16_t* ap = Ab + (size_t)s * 1024 + ln * 8;
      bf16x8 a0 = *(const bf16x8*)(ap);
      bf16x8 a1 = *(const bf16x8*)(ap + 512);
      const bf16_t* lp = &ldsB[p][j * 1536 + ln * 8];
      bf16x8 b0 = *(const bf16x8*)(lp);
      bf16x8 b1 = *(const bf16x8*)(lp + 512);
      bf16x8 b2 = *(const bf16x8*)(lp + 1024);
      acc[0][0] = MFMA16(a0, b0, acc[0][0]);
      acc[0][1] = MFMA16(a0, b1, acc[0][1]);
      acc[0][2] = MFMA16(a0, b2, acc[0][2]);
      acc[1][0] = MFMA16(a1, b0, acc[1][0]);
      acc[1][1] = MFMA16(a1, b1, acc[1][1]);
      acc[1][2] = MFMA16(a1, b2, acc[1][2]);
    }
    __syncthreads();  // all reads of p done + next-chunk DMA drained
  }

  // ---- G frags from global (latency hides behind w-norm/softmax) ----
  const bf16_t* Gb = Gfrag + (size_t)i * 3072;
  bf16x8 ga[2][3];
#pragma unroll
  for (int kk = 0; kk < 2; ++kk)
#pragma unroll
    for (int nt = 0; nt < 3; ++nt)
      ga[kk][nt] = *(const bf16x8*)(Gb + ((size_t)(kk * 3 + nt) * 64 + ln) * 8);

  // ---- w-norm: sum_m leaky(raw)^2 per column ----
  float sinv[3];
#pragma unroll
  for (int nt = 0; nt < 3; ++nt) {
    bool padn = (nt == 2) && (l15 >= 4);
    float ns = 0.f;
#pragma unroll
    for (int mt = 0; mt < 2; ++mt)
#pragma unroll
      for (int rg = 0; rg < 4; ++rg) {
        float v = acc[mt][nt][rg];
        float l = (v > 0.f) ? v : 0.1f * v;
        int m = mt * 16 + qd * 4 + rg;
        if (m >= clen || padn) l = 0.f;
        ns += l * l;
      }
    ns += __shfl_xor(ns, 16, 64);
    ns += __shfl_xor(ns, 32, 64);
    sinv[nt] = SMOOTH / (sqrtf(ns) + EPSF);
  }

  // ---- softmax over r per row + S = sum attn*raw; acc := softmax wts ----
  float Srow[2][4];
#pragma unroll
  for (int mt = 0; mt < 2; ++mt)
#pragma unroll
    for (int rg = 0; rg < 4; ++rg) {
      int m = mt * 16 + qd * 4 + rg;
      bool mrow = (m >= clen);
      float z[3];
#pragma unroll
      for (int nt = 0; nt < 3; ++nt) {
        float v = acc[mt][nt][rg];
        float l = (v > 0.f) ? v : 0.1f * v;
        if (mrow) l = 0.f;
        float zz = l * sinv[nt];
        if (nt == 2 && l15 >= 4) zz = -1e30f;
        z[nt] = zz;
      }
      float mx = fmaxf(fmaxf(z[0], z[1]), z[2]);
#pragma unroll
      for (int off = 1; off < 16; off <<= 1) mx = fmaxf(mx, __shfl_xor(mx, off, 64));
      float e[3], es = 0.f;
#pragma unroll
      for (int nt = 0; nt < 3; ++nt) {
        e[nt] = __expf(z[nt] - mx);
        es += e[nt];
      }
#pragma unroll
      for (int off = 1; off < 16; off <<= 1) es += __shfl_xor(es, off, 64);
      float inv = 1.0f / es;
      float sac = 0.f;
#pragma unroll
      for (int nt = 0; nt < 3; ++nt) {
        float a = e[nt] * inv;
        sac += a * acc[mt][nt][rg];   // raw before overwrite
        acc[mt][nt][rg] = a;          // softmax weight
      }
#pragma unroll
      for (int off = 1; off < 16; off <<= 1) sac += __shfl_xor(sac, off, 64);
      Srow[mt][rg] = sac;
    }

  // ---- stage attn to scratch (A-frag order), within-wave only ----
  bf16_t* as = &ldsB[0][0] + wv * 2304;   // 32 rows x 72, per-wave region
#pragma unroll
  for (int mt = 0; mt < 2; ++mt)
#pragma unroll
    for (int nt = 0; nt < 3; ++nt)
#pragma unroll
      for (int rg = 0; rg < 4; ++rg)
        as[(mt * 16 + qd * 4 + rg) * 72 + nt * 16 + l15] = (bf16_t)acc[mt][nt][rg];
  {  // zero k in [48,64)
    bf16x8 z8;
#pragma unroll
    for (int q = 0; q < 8; ++q) z8[q] = (bf16_t)0.0f;
    *(bf16x8*)(as + (ln >> 1) * 72 + 48 + (ln & 1) * 8) = z8;
  }
  bf16x8 fa[2][2];
#pragma unroll
  for (int mt = 0; mt < 2; ++mt)
#pragma unroll
    for (int kk = 0; kk < 2; ++kk)
      fa[mt][kk] = *(const bf16x8*)(as + (mt * 16 + l15) * 72 + kk * 32 + qd * 8);

  // ---- Y = attn * G via MFMA; n2[m] = sum Y .* attn ----
  f32x4 y[2][3];
#pragma unroll
  for (int mt = 0; mt < 2; ++mt)
#pragma unroll
    for (int nt = 0; nt < 3; ++nt) {
      f32x4 zf = {0.f, 0.f, 0.f, 0.f};
      y[mt][nt] = zf;
    }
#pragma unroll
  for (int kk = 0; kk < 2; ++kk)
#pragma unroll
    for (int mt = 0; mt < 2; ++mt)
#pragma unroll
      for (int nt = 0; nt < 3; ++nt)
        y[mt][nt] = MFMA16(fa[mt][kk], ga[kk][nt], y[mt][nt]);

  float n2row[2][4];
#pragma unroll
  for (int mt = 0; mt < 2; ++mt)
#pragma unroll
    for (int rg = 0; rg < 4; ++rg) {
      float nn = 0.f;
#pragma unroll
      for (int nt = 0; nt < 3; ++nt) nn += y[mt][nt][rg] * acc[mt][nt][rg];
#pragma unroll
      for (int off = 1; off < 16; off <<= 1) nn += __shfl_xor(nn, off, 64);
      n2row[mt][rg] = nn;
    }

  // ---- final sim + store: lanes l15<2 write float4 each ----
  if (l15 < 2) {
    int mt = l15;
    f32x4 cn = *(const f32x4*)(capnorm + c * 32 + mt * 16 + qd * 4);
    f32x4 o;
#pragma unroll
    for (int rg = 0; rg < 4; ++rg) {
      float n2v = fmaxf(n2row[mt][rg], 0.f);
      float nrm = sqrtf(n2v);
      float den = nrm + EPSF;
      float w12 = Srow[mt][rg] / den;
      float w2 = nrm / den;
      float sim = w12 / fmaxf(cn[rg] * w2, EPSF);
      int m = mt * 16 + qd * 4 + rg;
      if (m >= clen) sim = -1.0f;
      o[rg] = sim;
    }
    *(f32x4*)(out + ((size_t)i * CDIM + c) * WDIM + mt * 16 + qd * 4) = o;
  }
}

// =====================================================================
extern "C" void kernel_launch(void* const* d_in, const int* in_sizes, int n_in,
                              void* d_out, int out_size, void* d_ws, size_t ws_size,
                              hipStream_t stream) {
  const float* imgs = (const float*)d_in[0];
  const float* caps = (const float*)d_in[1];
  const int* cap_lens = (const int*)d_in[3];
  float* out = (float*)d_out;

  char* ws = (char*)d_ws;
  bf16_t* imgsB = (bf16_t*)(ws + IMGSB_OFF);
  bf16_t* capsA = (bf16_t*)(ws + CAPSA_OFF);
  bf16_t* Gfrag = (bf16_t*)(ws + GF_OFF);
  float* capnorm = (float*)(ws + CAPN_OFF);

  prep_fused<<<128, 256, 0, stream>>>(imgs, caps, imgsB, capsA, Gfrag, capnorm);
  main_kernel<<<1024, 256, 0, stream>>>(capsA, imgsB, Gfrag, capnorm, cap_lens, out);
}

// Round 12
// 98.436 us; speedup vs baseline: 1.0517x; 1.0517x over previous
//
#include <hip/hip_runtime.h>
#include <hip/hip_bf16.h>

#define IDIM 64
#define RDIM 36
#define DDIM 1024
#define CDIM 64
#define WDIM 32
#define SMOOTH 9.0f
#define EPSF 1e-8f

typedef __bf16 bf16_t;
typedef __bf16 bf16x8 __attribute__((ext_vector_type(8)));
typedef __bf16 bf16x4 __attribute__((ext_vector_type(4)));
typedef float f32x4 __attribute__((ext_vector_type(4)));

#define MFMA16(a, b, c) __builtin_amdgcn_mfma_f32_16x16x32_bf16((a), (b), (c), 0, 0, 0)

// ---------- workspace layout (bytes) ----------
// imgsB: frag-permuted imgs, rows padded to 48 with zeros.
//   elem off = ((((i*4+wvk)*8+kk)*3+nt)*64 + lane)*8 ; lane=(qd*16+l15)
// capsA: ((((c*4+wvk)*8+kk)*2+mt)*64 + lane)*8
// Gfrag: bf16 B-layout frags of Gram, per i: [(kk*3+nt)*64+lane]*8, kk in {0,1}
#define IMGSB_OFF 0
#define IMGSB_BYTES (IDIM * 4 * 8 * 3 * 512 * 2)            // 6 MB
#define CAPSA_OFF (IMGSB_OFF + IMGSB_BYTES)
#define CAPSA_BYTES (CDIM * 4 * 8 * 2 * 512 * 2)            // 4 MB
#define GF_OFF    (CAPSA_OFF + CAPSA_BYTES)
#define GF_BYTES  (IDIM * 384 * 8 * 2)                      // 384 KB
#define CAPN_OFF  (GF_OFF + GF_BYTES)

// =====================================================================
// Kernel 1: FUSED prep + gram, 128 blocks.
// Blocks 0..63 (one image i): fp32->bf16 transpose/convert, frags to
// global AND LDS fragL; Gram via MFMA from fragL; Gfrag written.
// Blocks 64..127 (one caption c): caps convert + fp32 norms.
// =====================================================================
__global__ __launch_bounds__(256) void prep_fused(
    const float* __restrict__ imgs, const float* __restrict__ caps,
    bf16_t* __restrict__ imgsB, bf16_t* __restrict__ capsA,
    bf16_t* __restrict__ Gfrag, float* __restrict__ capnorm) {
  __shared__ __align__(16) char smem0[4 * 48 * 49 * 4];   // ldsb | part overlay
  __shared__ __align__(16) bf16_t fragL[4][12288];        // 96 KB frag copy
  bf16_t* ldsb = (bf16_t*)smem0;                          // [36*264]
  float (*part)[48][49] = (float(*)[48][49])smem0;        // [4][48][49]

  int b = blockIdx.x, tid = threadIdx.x;
  int wv = tid >> 6, ln = tid & 63;
  int l15 = ln & 15, qd = ln >> 4;

  if (b < 64) {
    int i = b;
    // ---- phase 1: convert/transpose 4 K-slices ----
    for (int wvk = 0; wvk < 4; ++wvk) {
      const float* src = imgs + (size_t)i * RDIM * DDIM + wvk * 256;
#pragma unroll
      for (int rep = 0; rep < 9; ++rep) {          // 36 rows x 64 float4
        int idx = rep * 256 + tid;
        int row = idx >> 6, q = idx & 63;
        float4 v = *(const float4*)(src + (size_t)row * DDIM + q * 4);
        bf16x4 p;
        p[0] = (bf16_t)v.x; p[1] = (bf16_t)v.y; p[2] = (bf16_t)v.z; p[3] = (bf16_t)v.w;
        *(bf16x4*)&ldsb[row * 264 + q * 4] = p;
      }
      __syncthreads();
      bf16_t* dst = imgsB + (size_t)(i * 4 + wvk) * 12288;
#pragma unroll
      for (int rep = 0; rep < 6; ++rep) {          // 1536 frag units of 8
        int u = rep * 256 + tid;
        int kk = u / 192, rem = u - kk * 192;
        int nt = rem >> 6, lane = rem & 63, qd2 = lane >> 4, l152 = lane & 15;
        int row = nt * 16 + l152;
        bf16x8 p;
        if (row < 36) {
          p = *(const bf16x8*)&ldsb[row * 264 + kk * 32 + qd2 * 8];
        } else {
#pragma unroll
          for (int j = 0; j < 8; ++j) p[j] = (bf16_t)0.0f;
        }
        *(bf16x8*)(dst + (size_t)u * 8) = p;       // global, coalesced
        *(bf16x8*)&fragL[wvk][u * 8] = p;          // LDS copy for gram
      }
      __syncthreads();
    }
    // ---- phase 2: Gram via MFMA from fragL ----
    f32x4 acc[3][3];
#pragma unroll
    for (int mt = 0; mt < 3; ++mt)
#pragma unroll
      for (int nt = 0; nt < 3; ++nt) {
        f32x4 zf = {0.f, 0.f, 0.f, 0.f};
        acc[mt][nt] = zf;
      }
#pragma unroll
    for (int kk = 0; kk < 8; ++kk) {
      bf16x8 a[3];
#pragma unroll
      for (int nt = 0; nt < 3; ++nt)
        a[nt] = *(const bf16x8*)&fragL[wv][((kk * 3 + nt) * 64 + ln) * 8];
#pragma unroll
      for (int mt = 0; mt < 3; ++mt)
#pragma unroll
        for (int nt = 0; nt < 3; ++nt)
          acc[mt][nt] = MFMA16(a[mt], a[nt], acc[mt][nt]);
    }
#pragma unroll
    for (int mt = 0; mt < 3; ++mt)
#pragma unroll
      for (int nt = 0; nt < 3; ++nt)
#pragma unroll
        for (int rg = 0; rg < 4; ++rg)
          part[wv][mt * 16 + qd * 4 + rg][nt * 16 + l15] = acc[mt][nt][rg];
    __syncthreads();
    for (int idx = tid; idx < 384; idx += 256) {
      int kk = idx / 192;
      int rem = idx - kk * 192;
      int nt = rem >> 6, lnn = rem & 63;
      int qd2 = lnn >> 4, l152 = lnn & 15;
      int n = nt * 16 + l152;
      bf16x8 pk;
#pragma unroll
      for (int j = 0; j < 8; ++j) {
        int k = kk * 32 + qd2 * 8 + j;
        float v = (k < 48) ? (part[0][k][n] + part[1][k][n] + part[2][k][n] + part[3][k][n]) : 0.f;
        pk[j] = (bf16_t)v;
      }
      *(bf16x8*)(Gfrag + ((size_t)i * 384 + idx) * 8) = pk;
    }
  } else {
    // ---- caps branch: convert + fp32 norms ----
    int c = b - 64;
    const float* src = caps + (size_t)c * WDIM * DDIM;
    float ss[8];
#pragma unroll
    for (int rep = 0; rep < 8; ++rep) ss[rep] = 0.f;
    for (int wvk = 0; wvk < 4; ++wvk) {
#pragma unroll
      for (int rep = 0; rep < 8; ++rep) {          // 32 rows x 64 float4
        int idx = rep * 256 + tid;
        int row = idx >> 6, q = idx & 63;
        float4 v = *(const float4*)(src + (size_t)row * DDIM + wvk * 256 + q * 4);
        ss[rep] += v.x * v.x + v.y * v.y + v.z * v.z + v.w * v.w;
        bf16x4 p;
        p[0] = (bf16_t)v.x; p[1] = (bf16_t)v.y; p[2] = (bf16_t)v.z; p[3] = (bf16_t)v.w;
        *(bf16x4*)&ldsb[row * 264 + q * 4] = p;
      }
      __syncthreads();
      bf16_t* dst = capsA + (size_t)(c * 4 + wvk) * 8192;
#pragma unroll
      for (int rep = 0; rep < 4; ++rep) {          // 1024 frag units
        int u = rep * 256 + tid;
        int kk = u >> 7, rem = u & 127;
        int mt = rem >> 6, lane = rem & 63, qd2 = lane >> 4, l152 = lane & 15;
        int row = mt * 16 + l152;
        bf16x8 p = *(const bf16x8*)&ldsb[row * 264 + kk * 32 + qd2 * 8];
        *(bf16x8*)(dst + (size_t)u * 8) = p;
      }
      __syncthreads();
    }
#pragma unroll
    for (int rep = 0; rep < 8; ++rep) {
      float s = ss[rep];
#pragma unroll
      for (int off = 32; off >= 1; off >>= 1) s += __shfl_xor(s, off, 64);
      if (ln == rep) capnorm[c * 32 + rep * 4 + wv] = sqrtf(s);
    }
  }
}

// =====================================================================
// Kernel 2: main (R10 verbatim, best measured 98.7) — block = 4 waves
// = 4 c's x ONE i; B staged once into LDS via register double-buffer
// (loads for chunk k+1 issue BEFORE the MFMA block -> in flight across
// the compute; only the cheap ds_write sits before the barrier).
// =====================================================================
__global__ __launch_bounds__(256, 4) void main_kernel(
    const bf16_t* __restrict__ capsA, const bf16_t* __restrict__ imgsB,
    const bf16_t* __restrict__ Gfrag, const float* __restrict__ capnorm,
    const int* __restrict__ cap_lens, float* __restrict__ out) {
  __shared__ __align__(16) bf16_t ldsB[2][6144];   // 24.6 KB B chunks / attn scratch

  int bx = blockIdx.x;
  int wv = threadIdx.x >> 6, ln = threadIdx.x & 63;
  int l15 = ln & 15, qd = ln >> 4;
  int xcd = bx & 7, rest = bx >> 3;
  int ih = rest & 7, cq = rest >> 3;
  int i = xcd * 8 + ih;                 // XCD keeps an 8-image octet L2-resident
  int c = cq * 4 + wv;
  int clen = cap_lens[c];

  const bf16_t* Ab = capsA + (size_t)c * 32768;
  const bf16_t* Bb = imgsB + (size_t)i * 49152;

  // stage chunk 0 (each wave copies its 1536-elem quarter)
  bf16x8 t0, t1, t2;
  {
    const bf16_t* gp = Bb + wv * 1536 + ln * 8;
    t0 = *(const bf16x8*)(gp);
    t1 = *(const bf16x8*)(gp + 512);
    t2 = *(const bf16x8*)(gp + 1024);
    bf16_t* lp = &ldsB[0][wv * 1536 + ln * 8];
    *(bf16x8*)(lp) = t0;
    *(bf16x8*)(lp + 512) = t1;
    *(bf16x8*)(lp + 1024) = t2;
  }
  __syncthreads();

  f32x4 acc[2][3];
#pragma unroll
  for (int mt = 0; mt < 2; ++mt)
#pragma unroll
    for (int nt = 0; nt < 3; ++nt) {
      f32x4 zf = {0.f, 0.f, 0.f, 0.f};
      acc[mt][nt] = zf;
    }

  for (int ch = 0; ch < 8; ++ch) {
    int p = ch & 1;
    if (ch < 7) {  // prefetch next chunk quarter into regs
      const bf16_t* gp = Bb + (ch + 1) * 6144 + wv * 1536 + ln * 8;
      t0 = *(const bf16x8*)(gp);
      t1 = *(const bf16x8*)(gp + 512);
      t2 = *(const bf16x8*)(gp + 1024);
    }
#pragma unroll
    for (int j = 0; j < 4; ++j) {
      int s = ch * 4 + j;
      const bf16_t* ap = Ab + (size_t)s * 1024 + ln * 8;
      bf16x8 a0 = *(const bf16x8*)(ap);
      bf16x8 a1 = *(const bf16x8*)(ap + 512);
      const bf16_t* lp = &ldsB[p][j * 1536 + ln * 8];
      bf16x8 b0 = *(const bf16x8*)(lp);
      bf16x8 b1 = *(const bf16x8*)(lp + 512);
      bf16x8 b2 = *(const bf16x8*)(lp + 1024);
      acc[0][0] = MFMA16(a0, b0, acc[0][0]);
      acc[0][1] = MFMA16(a0, b1, acc[0][1]);
      acc[0][2] = MFMA16(a0, b2, acc[0][2]);
      acc[1][0] = MFMA16(a1, b0, acc[1][0]);
      acc[1][1] = MFMA16(a1, b1, acc[1][1]);
      acc[1][2] = MFMA16(a1, b2, acc[1][2]);
    }
    if (ch < 7) {
      bf16_t* lp = &ldsB[1 - p][wv * 1536 + ln * 8];
      *(bf16x8*)(lp) = t0;
      *(bf16x8*)(lp + 512) = t1;
      *(bf16x8*)(lp + 1024) = t2;
    }
    __syncthreads();
  }

  // ---- G frags from global (latency hides behind w-norm/softmax) ----
  const bf16_t* Gb = Gfrag + (size_t)i * 3072;
  bf16x8 ga[2][3];
#pragma unroll
  for (int kk = 0; kk < 2; ++kk)
#pragma unroll
    for (int nt = 0; nt < 3; ++nt)
      ga[kk][nt] = *(const bf16x8*)(Gb + ((size_t)(kk * 3 + nt) * 64 + ln) * 8);

  // ---- w-norm: sum_m leaky(raw)^2 per column ----
  float sinv[3];
#pragma unroll
  for (int nt = 0; nt < 3; ++nt) {
    bool padn = (nt == 2) && (l15 >= 4);
    float ns = 0.f;
#pragma unroll
    for (int mt = 0; mt < 2; ++mt)
#pragma unroll
      for (int rg = 0; rg < 4; ++rg) {
        float v = acc[mt][nt][rg];
        float l = (v > 0.f) ? v : 0.1f * v;
        int m = mt * 16 + qd * 4 + rg;
        if (m >= clen || padn) l = 0.f;
        ns += l * l;
      }
    ns += __shfl_xor(ns, 16, 64);
    ns += __shfl_xor(ns, 32, 64);
    sinv[nt] = SMOOTH / (sqrtf(ns) + EPSF);
  }

  // ---- softmax over r per row + S = sum attn*raw; acc := softmax wts ----
  float Srow[2][4];
#pragma unroll
  for (int mt = 0; mt < 2; ++mt)
#pragma unroll
    for (int rg = 0; rg < 4; ++rg) {
      int m = mt * 16 + qd * 4 + rg;
      bool mrow = (m >= clen);
      float z[3];
#pragma unroll
      for (int nt = 0; nt < 3; ++nt) {
        float v = acc[mt][nt][rg];
        float l = (v > 0.f) ? v : 0.1f * v;
        if (mrow) l = 0.f;
        float zz = l * sinv[nt];
        if (nt == 2 && l15 >= 4) zz = -1e30f;
        z[nt] = zz;
      }
      float mx = fmaxf(fmaxf(z[0], z[1]), z[2]);
#pragma unroll
      for (int off = 1; off < 16; off <<= 1) mx = fmaxf(mx, __shfl_xor(mx, off, 64));
      float e[3], es = 0.f;
#pragma unroll
      for (int nt = 0; nt < 3; ++nt) {
        e[nt] = __expf(z[nt] - mx);
        es += e[nt];
      }
#pragma unroll
      for (int off = 1; off < 16; off <<= 1) es += __shfl_xor(es, off, 64);
      float inv = 1.0f / es;
      float sac = 0.f;
#pragma unroll
      for (int nt = 0; nt < 3; ++nt) {
        float a = e[nt] * inv;
        sac += a * acc[mt][nt][rg];   // raw before overwrite
        acc[mt][nt][rg] = a;          // softmax weight
      }
#pragma unroll
      for (int off = 1; off < 16; off <<= 1) sac += __shfl_xor(sac, off, 64);
      Srow[mt][rg] = sac;
    }

  // ---- stage attn to scratch (A-frag order), within-wave only ----
  bf16_t* as = &ldsB[0][0] + wv * 2304;   // 32 rows x 72, per-wave region
#pragma unroll
  for (int mt = 0; mt < 2; ++mt)
#pragma unroll
    for (int nt = 0; nt < 3; ++nt)
#pragma unroll
      for (int rg = 0; rg < 4; ++rg)
        as[(mt * 16 + qd * 4 + rg) * 72 + nt * 16 + l15] = (bf16_t)acc[mt][nt][rg];
  {  // zero k in [48,64)
    bf16x8 z8;
#pragma unroll
    for (int q = 0; q < 8; ++q) z8[q] = (bf16_t)0.0f;
    *(bf16x8*)(as + (ln >> 1) * 72 + 48 + (ln & 1) * 8) = z8;
  }
  bf16x8 fa[2][2];
#pragma unroll
  for (int mt = 0; mt < 2; ++mt)
#pragma unroll
    for (int kk = 0; kk < 2; ++kk)
      fa[mt][kk] = *(const bf16x8*)(as + (mt * 16 + l15) * 72 + kk * 32 + qd * 8);

  // ---- Y = attn * G via MFMA; n2[m] = sum Y .* attn ----
  f32x4 y[2][3];
#pragma unroll
  for (int mt = 0; mt < 2; ++mt)
#pragma unroll
    for (int nt = 0; nt < 3; ++nt) {
      f32x4 zf = {0.f, 0.f, 0.f, 0.f};
      y[mt][nt] = zf;
    }
#pragma unroll
  for (int kk = 0; kk < 2; ++kk)
#pragma unroll
    for (int mt = 0; mt < 2; ++mt)
#pragma unroll
      for (int nt = 0; nt < 3; ++nt)
        y[mt][nt] = MFMA16(fa[mt][kk], ga[kk][nt], y[mt][nt]);

  float n2row[2][4];
#pragma unroll
  for (int mt = 0; mt < 2; ++mt)
#pragma unroll
    for (int rg = 0; rg < 4; ++rg) {
      float nn = 0.f;
#pragma unroll
      for (int nt = 0; nt < 3; ++nt) nn += y[mt][nt][rg] * acc[mt][nt][rg];
#pragma unroll
      for (int off = 1; off < 16; off <<= 1) nn += __shfl_xor(nn, off, 64);
      n2row[mt][rg] = nn;
    }

  // ---- final sim + store: lanes l15<2 write float4 each ----
  if (l15 < 2) {
    int mt = l15;
    f32x4 cn = *(const f32x4*)(capnorm + c * 32 + mt * 16 + qd * 4);
    f32x4 o;
#pragma unroll
    for (int rg = 0; rg < 4; ++rg) {
      float n2v = fmaxf(n2row[mt][rg], 0.f);
      float nrm = sqrtf(n2v);
      float den = nrm + EPSF;
      float w12 = Srow[mt][rg] / den;
      float w2 = nrm / den;
      float sim = w12 / fmaxf(cn[rg] * w2, EPSF);
      int m = mt * 16 + qd * 4 + rg;
      if (m >= clen) sim = -1.0f;
      o[rg] = sim;
    }
    *(f32x4*)(out + ((size_t)i * CDIM + c) * WDIM + mt * 16 + qd * 4) = o;
  }
}

// =====================================================================
extern "C" void kernel_launch(void* const* d_in, const int* in_sizes, int n_in,
                              void* d_out, int out_size, void* d_ws, size_t ws_size,
                              hipStream_t stream) {
  const float* imgs = (const float*)d_in[0];
  const float* caps = (const float*)d_in[1];
  const int* cap_lens = (const int*)d_in[3];
  float* out = (float*)d_out;

  char* ws = (char*)d_ws;
  bf16_t* imgsB = (bf16_t*)(ws + IMGSB_OFF);
  bf16_t* capsA = (bf16_t*)(ws + CAPSA_OFF);
  bf16_t* Gfrag = (bf16_t*)(ws + GF_OFF);
  float* capnorm = (float*)(ws + CAPN_OFF);

  prep_fused<<<128, 256, 0, stream>>>(imgs, caps, imgsB, capsA, Gfrag, capnorm);
  main_kernel<<<1024, 256, 0, stream>>>(capsA, imgsB, Gfrag, capnorm, cap_lens, out);
}